// Round 1
// baseline (7759.491 us; speedup 1.0000x reference)
//
#include <hip/hip_runtime.h>

typedef __bf16 bf16;
typedef __bf16 bf16x4 __attribute__((ext_vector_type(4)));
typedef __bf16 bf16x8 __attribute__((ext_vector_type(8)));
typedef float  f32x4  __attribute__((ext_vector_type(4)));
typedef unsigned long long u64;

#define MFMA(a,b,c) __builtin_amdgcn_mfma_f32_16x16x32_bf16((a),(b),(c),0,0,0)

// Problem dims
#define TSTEPS 512
#define NBATCH 128
#define DIN    256
#define DH     1024
#define NRANK  128
#define DOUT   256

// Workspace layout (bytes) — unchanged (ws_size proven sufficient)
#define ZI_OFF    0ull               // bf16 [512*128*1024]  = 134217728 B
#define QSEQ_OFF  134217728ull       // bf16 [512*128*128]   =  16777216 B
#define PBUF_OFF  150994944ull       // (unused this round)
#define WIN_OFF   151519232ull       // bf16 [1024*256]
#define U_OFF     152043520ull       // bf16 [128*1024]
#define V_OFF     152305664ull       // bf16 [1024*128]
#define WOUT_OFF  152567808ull       // bf16 [256*1024]
#define BAR_OFF   153092096ull       // (unused this round; k_prep still zeroes it)

// async global->LDS, 16B per lane, wave-uniform LDS base + lane*16 (HW rule)
__device__ __forceinline__ void gll16(const void* g, void* l) {
  __builtin_amdgcn_global_load_lds((const __attribute__((address_space(1))) unsigned int*)g,
                                   (__attribute__((address_space(3))) unsigned int*)l, 16, 0, 0);
}

// ---------------------------------------------------------------- K0: prep (unchanged)
__global__ __launch_bounds__(256) void k_prep(const float* __restrict__ W_in,
                                              const float* __restrict__ U,
                                              const float* __restrict__ V,
                                              const float* __restrict__ W_out,
                                              char* __restrict__ ws) {
  bf16* winb  = (bf16*)(ws + WIN_OFF);
  bf16* ub    = (bf16*)(ws + U_OFF);
  bf16* vb    = (bf16*)(ws + V_OFF);
  bf16* woutb = (bf16*)(ws + WOUT_OFF);
  bf16* qseq  = (bf16*)(ws + QSEQ_OFF);
  unsigned* bar = (unsigned*)(ws + BAR_OFF);
  size_t id = (size_t)blockIdx.x * 256 + threadIdx.x;
  if      (id < 262144) winb[id]           = (bf16)W_in[id];
  else if (id < 393216) ub[id - 262144]    = (bf16)U[id - 262144];
  else if (id < 524288) vb[id - 393216]    = (bf16)V[id - 393216];
  else if (id < 786432) woutb[id - 524288] = (bf16)W_out[id - 524288];
  else if (id < 802816) qseq[id - 786432]  = (bf16)0.0f;   // q_0 = 0
  else if (id < 802832) bar[id - 802816]   = 0u;
}

// ---------------------------------------------------------------- K1: zi = x @ W_in^T  (unchanged)
__global__ __launch_bounds__(256) void k_zi(const float* __restrict__ x,
                                            const char* __restrict__ ws,
                                            bf16* __restrict__ zi) {
  const bf16* winb = (const bf16*)(ws + WIN_OFF);
  __shared__ bf16 xl[128 * 264];
  __shared__ bf16 wl[128 * 264];
  const int tid = threadIdx.x, lane = tid & 63, wv = tid >> 6;
  const int q4 = lane >> 4, l16 = lane & 15;
  const int m0b = blockIdx.x * 128, n0 = blockIdx.y * 128;

  for (int ch = tid; ch < 8192; ch += 256) {
    int r = ch >> 6, c4 = ch & 63;
    float4 f = *(const float4*)&x[(size_t)(m0b + r) * 256 + c4 * 4];
    bf16x4 b; b[0] = (bf16)f.x; b[1] = (bf16)f.y; b[2] = (bf16)f.z; b[3] = (bf16)f.w;
    *(bf16x4*)&xl[r * 264 + c4 * 4] = b;
  }
  for (int ch = tid; ch < 4096; ch += 256) {
    int r = ch >> 5, c8 = ch & 31;
    *(uint4*)&wl[r * 264 + c8 * 8] = *(const uint4*)&winb[(size_t)(n0 + r) * 256 + c8 * 8];
  }
  __syncthreads();

  f32x4 z4 = {0.f, 0.f, 0.f, 0.f};
  f32x4 acc[2][8];
#pragma unroll
  for (int i = 0; i < 2; i++)
#pragma unroll
    for (int j = 0; j < 8; j++) acc[i][j] = z4;

  const int m0 = wv * 32;
#pragma unroll
  for (int kc = 0; kc < 8; kc++) {
    bf16x8 a0 = *(bf16x8*)&xl[(m0 + l16) * 264 + kc * 32 + q4 * 8];
    bf16x8 a1 = *(bf16x8*)&xl[(m0 + 16 + l16) * 264 + kc * 32 + q4 * 8];
#pragma unroll
    for (int nt = 0; nt < 8; nt++) {
      bf16x8 b = *(bf16x8*)&wl[(nt * 16 + l16) * 264 + kc * 32 + q4 * 8];
      acc[0][nt] = MFMA(a0, b, acc[0][nt]);
      acc[1][nt] = MFMA(a1, b, acc[1][nt]);
    }
  }
  __syncthreads();
#pragma unroll
  for (int mt = 0; mt < 2; mt++)
#pragma unroll
    for (int nt = 0; nt < 8; nt++)
#pragma unroll
      for (int r = 0; r < 4; r++) {
        int m = m0 + mt * 16 + q4 * 4 + r;
        int c = nt * 16 + l16;
        xl[m * 136 + c] = (bf16)acc[mt][nt][r];
      }
  __syncthreads();
  for (int ch = tid; ch < 2048; ch += 256) {
    int r = ch >> 4, c8 = ch & 15;
    *(uint4*)&zi[(size_t)(m0b + r) * 1024 + n0 + c8 * 8] = *(uint4*)&xl[r * 136 + c8 * 8];
  }
}

// ---------------------------------------------------------------- K2: batch-split sequential scan
// 4 independent workgroups; block g owns batch rows [g*32, g*32+32). NO inter-WG sync.
// Per step: loop 8 chunks of 128 h-cols; weights (V,U) streamed L2->LDS, double-buffered.
//   stage2: zh[32][128] = q_t @ V_chunk^T ; h = relu(zh + b + zi)  -> hl (LDS)
//   stage1: q_{t+1}[32][128] += h_chunk @ U_chunk^T  (fp32 MFMA accum over K=1024)
// LDS layouts XOR-swizzled: elem(row,col) = row*128 + (col ^ ((row&7)<<3))  (byte ^ (row&7)<<4).
// global_load_lds writes linearly -> source addresses are pre-inverse-swizzled (both-sides rule).
__global__ __launch_bounds__(1024) void k_scan(char* __restrict__ ws,
                                               const float* __restrict__ b_h) {
  const bf16* zi = (const bf16*)(ws + ZI_OFF);
  const bf16* ub = (const bf16*)(ws + U_OFF);
  const bf16* vb = (const bf16*)(ws + V_OFF);
  bf16* qseq = (bf16*)(ws + QSEQ_OFF);

  __shared__ __align__(16) bf16 wv2[2][16384];  // V chunk [128 hcol][128 rank], swizzled
  __shared__ __align__(16) bf16 wu2[2][16384];  // U chunk [128 rank][128 hcol], swizzled
  __shared__ __align__(16) bf16 hl2[2][4096];   // h chunk [32 b][128 hcol], swizzled
  __shared__ __align__(16) bf16 qlds[4096];     // q [32 b][128 rank], swizzled
  // total 155648 B <= 163840

  const int tid = threadIdx.x;
  const int lane = tid & 63, w = tid >> 6;          // 16 waves
  const int l16 = lane & 15, q4 = lane >> 4;
  const int mw = w >> 3, nw = w & 7;                // 2 m-tiles x 8 n-tiles
  const int brow0 = blockIdx.x * 32;

  // --- global_load_lds slot geometry: linear LDS dest, inverse-swizzled global src ---
  int vgo[2], ugr[2], ugc[2], lbase[2];
#pragma unroll
  for (int i = 0; i < 2; i++) {
    int e = (w * 2 + i) * 512 + lane * 8;           // linear LDS element this lane fills
    int r = e >> 7;
    int gc = (e & 127) ^ ((r & 7) << 3);            // inverse swizzle (involution)
    lbase[i] = (w * 2 + i) * 512;
    vgo[i] = r * 128 + gc;                          // V elem (+ jn*16384)
    ugr[i] = r; ugc[i] = gc;                        // U elem = r*1024 + jn*128 + gc
  }
  // --- fragment read offsets (elements, swizzled) ---
  int e2[4], eA[4];
#pragma unroll
  for (int kc = 0; kc < 4; kc++) {
    int kk = kc * 32 + q4 * 8;
    int r2 = nw * 16 + l16;                         // B rows (V hcol / U rank)
    int rA = mw * 16 + l16;                         // A rows (batch)
    e2[kc] = r2 * 128 + (kk ^ ((r2 & 7) << 3));
    eA[kc] = rA * 128 + (kk ^ ((rA & 7) << 3));
  }
  const int ccol = nw * 16 + l16;                   // C-frag col (n-dim)
  int ehw[4], zrow[4];
#pragma unroll
  for (int r = 0; r < 4; r++) {
    int m = mw * 16 + q4 * 4 + r;                   // C-frag row (batch)
    ehw[r] = m * 128 + (ccol ^ ((m & 7) << 3));
    zrow[r] = brow0 + m;
  }
  // bias per chunk (constant-indexed under unroll -> registers)
  float bj[8];
#pragma unroll
  for (int j = 0; j < 8; j++) bj[j] = b_h[j * 128 + ccol];

  // q_t register-resident as A-frags; q_0 = 0
  bf16x8 qa[4];
#pragma unroll
  for (int kc = 0; kc < 4; kc++)
#pragma unroll
    for (int u = 0; u < 8; u++) qa[kc][u] = (bf16)0.0f;
  f32x4 accq = {0.f, 0.f, 0.f, 0.f};
  bf16 zpf[2][4];                                    // zi prefetch ping-pong

  // prologue: issue chunk (t=0, j=0)
#pragma unroll
  for (int r = 0; r < 4; r++)
    zpf[0][r] = zi[(size_t)zrow[r] * 1024 + ccol];
#pragma unroll
  for (int i = 0; i < 2; i++) {
    gll16(&vb[vgo[i]], &wv2[0][lbase[i]]);
    gll16(&ub[(size_t)ugr[i] * 1024 + ugc[i]], &wu2[0][lbase[i]]);
  }

  for (int t = 0; t < TSTEPS - 1; t++) {
#pragma unroll
    for (int j = 0; j < 8; j++) {
      const int cb = j & 1, nb = cb ^ 1;
      const int jn = (j + 1) & 7;
      const int tn = (j == 7) ? (t + 1) : t;

      // own chunk-j loads done; then all waves' LDS writes visible
      asm volatile("s_waitcnt vmcnt(0)" ::: "memory");
      __builtin_amdgcn_sched_barrier(0);
      __builtin_amdgcn_s_barrier();
      __builtin_amdgcn_sched_barrier(0);

      // prefetch next chunk: zi -> regs, weights -> LDS[nb] (safe: chunk j-1 readers done)
#pragma unroll
      for (int r = 0; r < 4; r++)
        zpf[nb][r] = zi[((size_t)tn * NBATCH + zrow[r]) * 1024 + jn * 128 + ccol];
#pragma unroll
      for (int i = 0; i < 2; i++) {
        gll16(&vb[(size_t)jn * 16384 + vgo[i]], &wv2[nb][lbase[i]]);
        gll16(&ub[(size_t)ugr[i] * 1024 + jn * 128 + ugc[i]], &wu2[nb][lbase[i]]);
      }

      // ---- stage2: zh tile [16x16] per wave = q @ V_chunk^T (K=128)
      f32x4 accz = {0.f, 0.f, 0.f, 0.f};
#pragma unroll
      for (int kc = 0; kc < 4; kc++) {
        bf16x8 b = *(const bf16x8*)&wv2[cb][e2[kc]];
        accz = MFMA(qa[kc], b, accz);
      }
      // h = relu(zh + b + zi) -> hl (swizzled scalar writes)
#pragma unroll
      for (int r = 0; r < 4; r++) {
        float v = accz[r] + bj[j] + (float)zpf[cb][r];
        hl2[cb][ehw[r]] = (bf16)fmaxf(v, 0.0f);
      }

      asm volatile("s_waitcnt lgkmcnt(0)" ::: "memory");
      __builtin_amdgcn_sched_barrier(0);
      __builtin_amdgcn_s_barrier();
      __builtin_amdgcn_sched_barrier(0);

      // ---- stage1: q' tile [16x16] per wave += h_chunk @ U_chunk^T (K=128 this chunk)
#pragma unroll
      for (int kc = 0; kc < 4; kc++) {
        bf16x8 a = *(const bf16x8*)&hl2[cb][eA[kc]];
        bf16x8 b = *(const bf16x8*)&wu2[cb][e2[kc]];
        accq = MFMA(a, b, accq);
      }
    }

    // ---- step end: q_{t+1} -> qlds (next A-frags) + qseq (global, fire-and-forget)
#pragma unroll
    for (int r = 0; r < 4; r++) {
      bf16 qv = (bf16)accq[r];
      qlds[ehw[r]] = qv;
      qseq[(size_t)(t + 1) * (NBATCH * NRANK) + (size_t)zrow[r] * NRANK + ccol] = qv;
    }
    accq[0] = 0.f; accq[1] = 0.f; accq[2] = 0.f; accq[3] = 0.f;

    asm volatile("s_waitcnt lgkmcnt(0)" ::: "memory");
    __builtin_amdgcn_sched_barrier(0);
    __builtin_amdgcn_s_barrier();
    __builtin_amdgcn_sched_barrier(0);

#pragma unroll
    for (int kc = 0; kc < 4; kc++)
      qa[kc] = *(const bf16x8*)&qlds[eA[kc]];
  }
}

// ---------------------------------------------------------------- K3: hidden[t] = relu(q_t V^T + b + zi_t)  (unchanged)
__global__ __launch_bounds__(256) void k_hidden(const char* __restrict__ ws,
                                                const float* __restrict__ b_h,
                                                float* __restrict__ hid) {
  const bf16* qseq = (const bf16*)(ws + QSEQ_OFF);
  const bf16* vb   = (const bf16*)(ws + V_OFF);
  const bf16* zi   = (const bf16*)(ws + ZI_OFF);
  const int t = blockIdx.x, n0 = blockIdx.y * 128;
  const int tid = threadIdx.x, lane = tid & 63, wv = tid >> 6;
  const int q4 = lane >> 4, l16 = lane & 15;

  __shared__ bf16 ql2[128 * 136];
  __shared__ bf16 vl2[128 * 136];
  __shared__ bf16 zl2[128 * 136];
  __shared__ float bl2[128];

  for (int ch = tid; ch < 2048; ch += 256) {
    int r = ch >> 4, c8 = ch & 15;
    *(uint4*)&ql2[r * 136 + c8 * 8] = *(const uint4*)&qseq[(size_t)t * 16384 + r * 128 + c8 * 8];
    *(uint4*)&vl2[r * 136 + c8 * 8] = *(const uint4*)&vb[(size_t)(n0 + r) * 128 + c8 * 8];
    *(uint4*)&zl2[r * 136 + c8 * 8] = *(const uint4*)&zi[((size_t)t * 128 + r) * 1024 + n0 + c8 * 8];
  }
  if (tid < 128) bl2[tid] = b_h[n0 + tid];
  __syncthreads();

  f32x4 z4 = {0.f, 0.f, 0.f, 0.f};
  f32x4 acc[2][8];
#pragma unroll
  for (int i = 0; i < 2; i++)
#pragma unroll
    for (int j = 0; j < 8; j++) acc[i][j] = z4;

  const int m0 = wv * 32;
#pragma unroll
  for (int kc = 0; kc < 4; kc++) {
    bf16x8 a0 = *(bf16x8*)&ql2[(m0 + l16) * 136 + kc * 32 + q4 * 8];
    bf16x8 a1 = *(bf16x8*)&ql2[(m0 + 16 + l16) * 136 + kc * 32 + q4 * 8];
#pragma unroll
    for (int nt = 0; nt < 8; nt++) {
      bf16x8 b = *(bf16x8*)&vl2[(nt * 16 + l16) * 136 + kc * 32 + q4 * 8];
      acc[0][nt] = MFMA(a0, b, acc[0][nt]);
      acc[1][nt] = MFMA(a1, b, acc[1][nt]);
    }
  }
#pragma unroll
  for (int mt = 0; mt < 2; mt++)
#pragma unroll
    for (int nt = 0; nt < 8; nt++)
#pragma unroll
      for (int r = 0; r < 4; r++) {
        int m = m0 + mt * 16 + q4 * 4 + r;
        int c = nt * 16 + l16;
        float v = acc[mt][nt][r] + bl2[c] + (float)zl2[m * 136 + c];
        hid[((size_t)t * 128 + m) * 1024 + n0 + c] = fmaxf(v, 0.0f);
      }
}

// ---------------------------------------------------------------- K4: output = hidden @ W_out^T + b_out (unchanged)
__global__ __launch_bounds__(512) void k_out(const char* __restrict__ ws,
                                             const float* __restrict__ hid,
                                             const float* __restrict__ b_out,
                                             float* __restrict__ out) {
  const bf16* woutb = (const bf16*)(ws + WOUT_OFF);
  const int t = blockIdx.x;
  const int tid = threadIdx.x, lane = tid & 63, wv = tid >> 6;  // 8 waves
  const int q4 = lane >> 4, l16 = lane & 15;

  __shared__ bf16 hl2[128 * 136];
  __shared__ bf16 wl2[256 * 136];
  __shared__ float bol[256];
  if (tid < 256) bol[tid] = b_out[tid];

  f32x4 z4 = {0.f, 0.f, 0.f, 0.f};
  f32x4 acc[16];
#pragma unroll
  for (int j = 0; j < 16; j++) acc[j] = z4;

  const int m0 = wv * 16;
  for (int k0 = 0; k0 < 1024; k0 += 128) {
    __syncthreads();
    for (int ch = tid; ch < 4096; ch += 512) {
      int r = ch >> 5, c4 = ch & 31;
      float4 f = *(const float4*)&hid[((size_t)t * 128 + r) * 1024 + k0 + c4 * 4];
      bf16x4 b; b[0] = (bf16)f.x; b[1] = (bf16)f.y; b[2] = (bf16)f.z; b[3] = (bf16)f.w;
      *(bf16x4*)&hl2[r * 136 + c4 * 4] = b;
    }
    for (int ch = tid; ch < 4096; ch += 512) {
      int r = ch >> 4, c8 = ch & 15;
      *(uint4*)&wl2[r * 136 + c8 * 8] = *(const uint4*)&woutb[(size_t)r * 1024 + k0 + c8 * 8];
    }
    __syncthreads();
#pragma unroll
    for (int kc = 0; kc < 4; kc++) {
      bf16x8 a = *(bf16x8*)&hl2[(m0 + l16) * 136 + kc * 32 + q4 * 8];
#pragma unroll
      for (int nt = 0; nt < 16; nt++) {
        bf16x8 b = *(bf16x8*)&wl2[(nt * 16 + l16) * 136 + kc * 32 + q4 * 8];
        acc[nt] = MFMA(a, b, acc[nt]);
      }
    }
  }
#pragma unroll
  for (int nt = 0; nt < 16; nt++)
#pragma unroll
    for (int r = 0; r < 4; r++) {
      int m = m0 + q4 * 4 + r;
      int c = nt * 16 + l16;
      out[((size_t)t * 128 + m) * 256 + c] = acc[nt][r] + bol[c];
    }
}

// ---------------------------------------------------------------- launch
extern "C" void kernel_launch(void* const* d_in, const int* in_sizes, int n_in,
                              void* d_out, int out_size, void* d_ws, size_t ws_size,
                              hipStream_t stream) {
  (void)in_sizes; (void)n_in; (void)out_size; (void)ws_size;
  const float* x     = (const float*)d_in[0];
  const float* W_in  = (const float*)d_in[1];
  const float* U     = (const float*)d_in[2];
  const float* V     = (const float*)d_in[3];
  const float* b_h   = (const float*)d_in[4];
  const float* W_out = (const float*)d_in[5];
  const float* b_out = (const float*)d_in[6];
  char* ws = (char*)d_ws;
  float* hid = (float*)d_out;
  float* out = hid + (size_t)TSTEPS * NBATCH * DH;
  bf16* zi = (bf16*)(ws + ZI_OFF);

  k_prep<<<dim3(3137), dim3(256), 0, stream>>>(W_in, U, V, W_out, ws);
  k_zi<<<dim3(512, 8), dim3(256), 0, stream>>>(x, ws, zi);
  k_scan<<<dim3(4), dim3(1024), 0, stream>>>(ws, b_h);
  k_hidden<<<dim3(512, 8), dim3(256), 0, stream>>>(ws, b_h, hid);
  k_out<<<dim3(512), dim3(512), 0, stream>>>(ws, hid, b_out, out);
}

// Round 2
// 2505.129 us; speedup vs baseline: 3.0974x; 3.0974x over previous
//
#include <hip/hip_runtime.h>

typedef __bf16 bf16;
typedef __bf16 bf16x4 __attribute__((ext_vector_type(4)));
typedef __bf16 bf16x8 __attribute__((ext_vector_type(8)));
typedef float  f32x4  __attribute__((ext_vector_type(4)));
typedef unsigned long long u64;

#define MFMA(a,b,c) __builtin_amdgcn_mfma_f32_16x16x32_bf16((a),(b),(c),0,0,0)

// Problem dims
#define TSTEPS 512
#define NBATCH 128
#define DIN    256
#define DH     1024
#define NRANK  128
#define DOUT   256

// Scan decomposition: 8 batch-groups x 4 hidden-groups = 32 WGs.
// WG (bg,g) owns batch rows [bg*16,+16) and h-cols [g*256,+256).
#define NBG 8
#define NGH 4

// Workspace layout (bytes) — identical footprint to previous rounds.
#define ZI_OFF    0ull               // bf16 [512*128*1024]  = 134217728 B
#define QSEQ_OFF  134217728ull       // bf16 [512*128*128]   =  16777216 B
#define PBUF_OFF  150994944ull       // partials [2][8][4][16][128] bf16 = 262144 B, then 32 flags
#define FLAG_OFF  (PBUF_OFF + 262144ull)
#define WIN_OFF   151519232ull       // bf16 [1024*256]
#define U_OFF     152043520ull       // bf16 [128*1024]
#define V_OFF     152305664ull       // bf16 [1024*128]
#define WOUT_OFF  152567808ull       // bf16 [256*1024]
#define BAR_OFF   153092096ull       // legacy (unused)

// Coherent (agent-scope, cache-bypassing) 8-byte access helpers (proven pattern).
__device__ __forceinline__ void cstore64(u64* p, u64 v) {
  __hip_atomic_store(p, v, __ATOMIC_RELAXED, __HIP_MEMORY_SCOPE_AGENT);
}
__device__ __forceinline__ u64 cload64(const u64* p) {
  return __hip_atomic_load(p, __ATOMIC_RELAXED, __HIP_MEMORY_SCOPE_AGENT);
}
union B4U { u64 u; bf16x4 b; };

// ---------------------------------------------------------------- K0: prep
__global__ __launch_bounds__(256) void k_prep(const float* __restrict__ W_in,
                                              const float* __restrict__ U,
                                              const float* __restrict__ V,
                                              const float* __restrict__ W_out,
                                              char* __restrict__ ws) {
  bf16* winb  = (bf16*)(ws + WIN_OFF);
  bf16* ub    = (bf16*)(ws + U_OFF);
  bf16* vb    = (bf16*)(ws + V_OFF);
  bf16* woutb = (bf16*)(ws + WOUT_OFF);
  bf16* qseq  = (bf16*)(ws + QSEQ_OFF);
  unsigned* flg = (unsigned*)(ws + FLAG_OFF);
  size_t id = (size_t)blockIdx.x * 256 + threadIdx.x;
  if      (id < 262144) winb[id]           = (bf16)W_in[id];
  else if (id < 393216) ub[id - 262144]    = (bf16)U[id - 262144];
  else if (id < 524288) vb[id - 393216]    = (bf16)V[id - 393216];
  else if (id < 786432) woutb[id - 524288] = (bf16)W_out[id - 524288];
  else if (id < 802816) qseq[id - 786432]  = (bf16)0.0f;   // q_0 = 0
  else if (id < 802848) flg[id - 802816]   = 0u;           // 32 sync flags
}

// ---------------------------------------------------------------- K1: zi = x @ W_in^T  (unchanged)
__global__ __launch_bounds__(256) void k_zi(const float* __restrict__ x,
                                            const char* __restrict__ ws,
                                            bf16* __restrict__ zi) {
  const bf16* winb = (const bf16*)(ws + WIN_OFF);
  __shared__ bf16 xl[128 * 264];
  __shared__ bf16 wl[128 * 264];
  const int tid = threadIdx.x, lane = tid & 63, wv = tid >> 6;
  const int q4 = lane >> 4, l16 = lane & 15;
  const int m0b = blockIdx.x * 128, n0 = blockIdx.y * 128;

  for (int ch = tid; ch < 8192; ch += 256) {
    int r = ch >> 6, c4 = ch & 63;
    float4 f = *(const float4*)&x[(size_t)(m0b + r) * 256 + c4 * 4];
    bf16x4 b; b[0] = (bf16)f.x; b[1] = (bf16)f.y; b[2] = (bf16)f.z; b[3] = (bf16)f.w;
    *(bf16x4*)&xl[r * 264 + c4 * 4] = b;
  }
  for (int ch = tid; ch < 4096; ch += 256) {
    int r = ch >> 5, c8 = ch & 31;
    *(uint4*)&wl[r * 264 + c8 * 8] = *(const uint4*)&winb[(size_t)(n0 + r) * 256 + c8 * 8];
  }
  __syncthreads();

  f32x4 z4 = {0.f, 0.f, 0.f, 0.f};
  f32x4 acc[2][8];
#pragma unroll
  for (int i = 0; i < 2; i++)
#pragma unroll
    for (int j = 0; j < 8; j++) acc[i][j] = z4;

  const int m0 = wv * 32;
#pragma unroll
  for (int kc = 0; kc < 8; kc++) {
    bf16x8 a0 = *(bf16x8*)&xl[(m0 + l16) * 264 + kc * 32 + q4 * 8];
    bf16x8 a1 = *(bf16x8*)&xl[(m0 + 16 + l16) * 264 + kc * 32 + q4 * 8];
#pragma unroll
    for (int nt = 0; nt < 8; nt++) {
      bf16x8 b = *(bf16x8*)&wl[(nt * 16 + l16) * 264 + kc * 32 + q4 * 8];
      acc[0][nt] = MFMA(a0, b, acc[0][nt]);
      acc[1][nt] = MFMA(a1, b, acc[1][nt]);
    }
  }
  __syncthreads();
#pragma unroll
  for (int mt = 0; mt < 2; mt++)
#pragma unroll
    for (int nt = 0; nt < 8; nt++)
#pragma unroll
      for (int r = 0; r < 4; r++) {
        int m = m0 + mt * 16 + q4 * 4 + r;
        int c = nt * 16 + l16;
        xl[m * 136 + c] = (bf16)acc[mt][nt][r];
      }
  __syncthreads();
  for (int ch = tid; ch < 2048; ch += 256) {
    int r = ch >> 4, c8 = ch & 15;
    *(uint4*)&zi[(size_t)(m0b + r) * 1024 + n0 + c8 * 8] = *(uint4*)&xl[r * 136 + c8 * 8];
  }
}

// ---------------------------------------------------------------- K2: batch x hidden split scan
// 32 WGs, weights LDS-resident, ONE sync round per step (4-WG groups),
// parity double-buffered partials (no second ack round needed).
__global__ __launch_bounds__(256) void k_scan(char* __restrict__ ws,
                                              const float* __restrict__ b_h) {
  const bf16* zi = (const bf16*)(ws + ZI_OFF);
  const bf16* ub = (const bf16*)(ws + U_OFF);
  const bf16* vb = (const bf16*)(ws + V_OFF);
  bf16* qseq = (bf16*)(ws + QSEQ_OFF);
  u64* pbufq = (u64*)(ws + PBUF_OFF);              // [2][8][4][512] u64
  unsigned* flag = (unsigned*)(ws + FLAG_OFF);     // [8][4]

  __shared__ bf16 Vl[256 * 136];   // V[hcol0+r][k]   69632 B
  __shared__ bf16 Ul[128 * 264];   // U[r][hcol0+c]   67584 B
  __shared__ bf16 ql[16 * 136];    // q_t [row][rank]  4352 B
  __shared__ bf16 hl[16 * 264];    // h   [row][hcol]  8448 B
  __shared__ bf16 ps[16 * 136];    // partial staging  4352 B
  // total 154368 B

  const int tid = threadIdx.x, lane = tid & 63, w = tid >> 6;   // 4 waves
  const int l16 = lane & 15, q4 = lane >> 4;
  const int bg = blockIdx.x & 7, g = blockIdx.x >> 3;           // group siblings share XCD
  const int brow0 = bg * 16, hcol0 = g * 256;

  // ---- stage weights (one-time, L2 -> LDS)
  for (int ch = tid; ch < 4096; ch += 256) {
    int r = ch >> 4, c8 = ch & 15;
    *(uint4*)&Vl[r * 136 + c8 * 8] = *(const uint4*)&vb[(size_t)(hcol0 + r) * 128 + c8 * 8];
  }
  for (int ch = tid; ch < 4096; ch += 256) {
    int r = ch >> 5, c8 = ch & 31;
    *(uint4*)&Ul[r * 264 + c8 * 8] = *(const uint4*)&ub[(size_t)r * 1024 + hcol0 + c8 * 8];
  }
  for (int i = tid; i < 16 * 136; i += 256) ql[i] = (bf16)0.0f;   // q_0 = 0

  float bj[4];
#pragma unroll
  for (int nt = 0; nt < 4; nt++) bj[nt] = b_h[hcol0 + w * 64 + nt * 16 + l16];

  // zi prefetch registers (this thread's stage2 C-frag positions)
  bf16 zcur[16], znxt[16];
#pragma unroll
  for (int nt = 0; nt < 4; nt++)
#pragma unroll
    for (int rr = 0; rr < 4; rr++)
      zcur[nt * 4 + rr] = zi[(size_t)(brow0 + q4 * 4 + rr) * 1024 + hcol0 + w * 64 + nt * 16 + l16];
  __syncthreads();

  const f32x4 z4 = {0.f, 0.f, 0.f, 0.f};

  for (int t = 0; t < TSTEPS - 1; t++) {
    // ---- stage2: zh[16][256] = q_t @ V_g^T ; h = relu(zh + b + zi_t)
    f32x4 az[4] = {z4, z4, z4, z4};
#pragma unroll
    for (int kc = 0; kc < 4; kc++) {
      bf16x8 a = *(const bf16x8*)&ql[l16 * 136 + kc * 32 + q4 * 8];
#pragma unroll
      for (int nt = 0; nt < 4; nt++) {
        bf16x8 bb = *(const bf16x8*)&Vl[(w * 64 + nt * 16 + l16) * 136 + kc * 32 + q4 * 8];
        az[nt] = MFMA(a, bb, az[nt]);
      }
    }
#pragma unroll
    for (int nt = 0; nt < 4; nt++)
#pragma unroll
      for (int rr = 0; rr < 4; rr++) {
        float v = az[nt][rr] + bj[nt] + (float)zcur[nt * 4 + rr];
        hl[(q4 * 4 + rr) * 264 + w * 64 + nt * 16 + l16] = (bf16)fmaxf(v, 0.0f);
      }
    __syncthreads();

    // ---- stage1: partial[16][128] = h @ U_g^T  (K = 256)
    f32x4 ap[2] = {z4, z4};
#pragma unroll
    for (int kc = 0; kc < 8; kc++) {
      bf16x8 a = *(const bf16x8*)&hl[l16 * 264 + kc * 32 + q4 * 8];
#pragma unroll
      for (int nt = 0; nt < 2; nt++) {
        bf16x8 bb = *(const bf16x8*)&Ul[(w * 32 + nt * 16 + l16) * 264 + kc * 32 + q4 * 8];
        ap[nt] = MFMA(a, bb, ap[nt]);
      }
    }
#pragma unroll
    for (int nt = 0; nt < 2; nt++)
#pragma unroll
      for (int rr = 0; rr < 4; rr++)
        ps[(q4 * 4 + rr) * 136 + w * 32 + nt * 16 + l16] = (bf16)ap[nt][rr];
    __syncthreads();

    // ---- publish partial (coherent), parity double-buffered
    const int par = t & 1;
    u64* mybuf = &pbufq[(size_t)((par * NBG + bg) * NGH + g) * 512];
#pragma unroll
    for (int i = 0; i < 2; i++) {
      int e = tid + i * 256;
      int r = e >> 5, c4 = e & 31;
      cstore64(&mybuf[e], *(const u64*)&ps[r * 136 + c4 * 4]);
    }
    __syncthreads();   // drains vmcnt for ALL waves -> partial at coherence point
    if (tid == 0)
      __hip_atomic_store(&flag[bg * 4 + g], (unsigned)(t + 1), __ATOMIC_RELEASE, __HIP_MEMORY_SCOPE_AGENT);

    // prefetch zi[t+1] (normal cached loads; drained by the barrier below, hidden under poll)
#pragma unroll
    for (int nt = 0; nt < 4; nt++)
#pragma unroll
      for (int rr = 0; rr < 4; rr++)
        znxt[nt * 4 + rr] =
            zi[((size_t)(t + 1) * NBATCH + brow0 + q4 * 4 + rr) * 1024 + hcol0 + w * 64 + nt * 16 + l16];

    if (tid < NGH) {
      while (__hip_atomic_load(&flag[bg * 4 + tid], __ATOMIC_RELAXED, __HIP_MEMORY_SCOPE_AGENT) <
             (unsigned)(t + 1)) {}
    }
    __syncthreads();

    // ---- reduce 4 partials -> q_{t+1}; install into ql (+ qseq by g==0)
    const u64* base = &pbufq[(size_t)(par * NBG + bg) * NGH * 512];
#pragma unroll
    for (int i = 0; i < 2; i++) {
      int e = tid + i * 256;
      int r = e >> 5, c4 = e & 31;
      float s0 = 0.f, s1 = 0.f, s2 = 0.f, s3 = 0.f;
#pragma unroll
      for (int p = 0; p < NGH; p++) {
        B4U v; v.u = cload64(&base[(size_t)p * 512 + e]);
        s0 += (float)v.b[0]; s1 += (float)v.b[1]; s2 += (float)v.b[2]; s3 += (float)v.b[3];
      }
      B4U o; o.b[0] = (bf16)s0; o.b[1] = (bf16)s1; o.b[2] = (bf16)s2; o.b[3] = (bf16)s3;
      *(bf16x4*)&ql[r * 136 + c4 * 4] = o.b;
      if (g == 0)
        *(u64*)&qseq[((size_t)(t + 1) * NBATCH + brow0 + r) * 128 + c4 * 4] = o.u;
    }
    __syncthreads();
#pragma unroll
    for (int k = 0; k < 16; k++) zcur[k] = znxt[k];
  }
}

// ---------------------------------------------------------------- K3: hidden[t] = relu(q_t V^T + b + zi_t)  (unchanged)
__global__ __launch_bounds__(256) void k_hidden(const char* __restrict__ ws,
                                                const float* __restrict__ b_h,
                                                float* __restrict__ hid) {
  const bf16* qseq = (const bf16*)(ws + QSEQ_OFF);
  const bf16* vb   = (const bf16*)(ws + V_OFF);
  const bf16* zi   = (const bf16*)(ws + ZI_OFF);
  const int t = blockIdx.x, n0 = blockIdx.y * 128;
  const int tid = threadIdx.x, lane = tid & 63, wv = tid >> 6;
  const int q4 = lane >> 4, l16 = lane & 15;

  __shared__ bf16 ql2[128 * 136];
  __shared__ bf16 vl2[128 * 136];
  __shared__ bf16 zl2[128 * 136];
  __shared__ float bl2[128];

  for (int ch = tid; ch < 2048; ch += 256) {
    int r = ch >> 4, c8 = ch & 15;
    *(uint4*)&ql2[r * 136 + c8 * 8] = *(const uint4*)&qseq[(size_t)t * 16384 + r * 128 + c8 * 8];
    *(uint4*)&vl2[r * 136 + c8 * 8] = *(const uint4*)&vb[(size_t)(n0 + r) * 128 + c8 * 8];
    *(uint4*)&zl2[r * 136 + c8 * 8] = *(const uint4*)&zi[((size_t)t * 128 + r) * 1024 + n0 + c8 * 8];
  }
  if (tid < 128) bl2[tid] = b_h[n0 + tid];
  __syncthreads();

  f32x4 z4 = {0.f, 0.f, 0.f, 0.f};
  f32x4 acc[2][8];
#pragma unroll
  for (int i = 0; i < 2; i++)
#pragma unroll
    for (int j = 0; j < 8; j++) acc[i][j] = z4;

  const int m0 = wv * 32;
#pragma unroll
  for (int kc = 0; kc < 4; kc++) {
    bf16x8 a0 = *(bf16x8*)&ql2[(m0 + l16) * 136 + kc * 32 + q4 * 8];
    bf16x8 a1 = *(bf16x8*)&ql2[(m0 + 16 + l16) * 136 + kc * 32 + q4 * 8];
#pragma unroll
    for (int nt = 0; nt < 8; nt++) {
      bf16x8 b = *(bf16x8*)&vl2[(nt * 16 + l16) * 136 + kc * 32 + q4 * 8];
      acc[0][nt] = MFMA(a0, b, acc[0][nt]);
      acc[1][nt] = MFMA(a1, b, acc[1][nt]);
    }
  }
#pragma unroll
  for (int mt = 0; mt < 2; mt++)
#pragma unroll
    for (int nt = 0; nt < 8; nt++)
#pragma unroll
      for (int r = 0; r < 4; r++) {
        int m = m0 + mt * 16 + q4 * 4 + r;
        int c = nt * 16 + l16;
        float v = acc[mt][nt][r] + bl2[c] + (float)zl2[m * 136 + c];
        hid[((size_t)t * 128 + m) * 1024 + n0 + c] = fmaxf(v, 0.0f);
      }
}

// ---------------------------------------------------------------- K4: output = hidden @ W_out^T + b_out (unchanged)
__global__ __launch_bounds__(512) void k_out(const char* __restrict__ ws,
                                             const float* __restrict__ hid,
                                             const float* __restrict__ b_out,
                                             float* __restrict__ out) {
  const bf16* woutb = (const bf16*)(ws + WOUT_OFF);
  const int t = blockIdx.x;
  const int tid = threadIdx.x, lane = tid & 63, wv = tid >> 6;  // 8 waves
  const int q4 = lane >> 4, l16 = lane & 15;

  __shared__ bf16 hl2[128 * 136];
  __shared__ bf16 wl2[256 * 136];
  __shared__ float bol[256];
  if (tid < 256) bol[tid] = b_out[tid];

  f32x4 z4 = {0.f, 0.f, 0.f, 0.f};
  f32x4 acc[16];
#pragma unroll
  for (int j = 0; j < 16; j++) acc[j] = z4;

  const int m0 = wv * 16;
  for (int k0 = 0; k0 < 1024; k0 += 128) {
    __syncthreads();
    for (int ch = tid; ch < 4096; ch += 512) {
      int r = ch >> 5, c4 = ch & 31;
      float4 f = *(const float4*)&hid[((size_t)t * 128 + r) * 1024 + k0 + c4 * 4];
      bf16x4 b; b[0] = (bf16)f.x; b[1] = (bf16)f.y; b[2] = (bf16)f.z; b[3] = (bf16)f.w;
      *(bf16x4*)&hl2[r * 136 + c4 * 4] = b;
    }
    for (int ch = tid; ch < 4096; ch += 512) {
      int r = ch >> 4, c8 = ch & 15;
      *(uint4*)&wl2[r * 136 + c8 * 8] = *(const uint4*)&woutb[(size_t)r * 1024 + k0 + c8 * 8];
    }
    __syncthreads();
#pragma unroll
    for (int kc = 0; kc < 4; kc++) {
      bf16x8 a = *(bf16x8*)&hl2[(m0 + l16) * 136 + kc * 32 + q4 * 8];
#pragma unroll
      for (int nt = 0; nt < 16; nt++) {
        bf16x8 b = *(bf16x8*)&wl2[(nt * 16 + l16) * 136 + kc * 32 + q4 * 8];
        acc[nt] = MFMA(a, b, acc[nt]);
      }
    }
  }
#pragma unroll
  for (int nt = 0; nt < 16; nt++)
#pragma unroll
    for (int r = 0; r < 4; r++) {
      int m = m0 + q4 * 4 + r;
      int c = nt * 16 + l16;
      out[((size_t)t * 128 + m) * 256 + c] = acc[nt][r] + bol[c];
    }
}

// ---------------------------------------------------------------- launch
extern "C" void kernel_launch(void* const* d_in, const int* in_sizes, int n_in,
                              void* d_out, int out_size, void* d_ws, size_t ws_size,
                              hipStream_t stream) {
  (void)in_sizes; (void)n_in; (void)out_size; (void)ws_size;
  const float* x     = (const float*)d_in[0];
  const float* W_in  = (const float*)d_in[1];
  const float* U     = (const float*)d_in[2];
  const float* V     = (const float*)d_in[3];
  const float* b_h   = (const float*)d_in[4];
  const float* W_out = (const float*)d_in[5];
  const float* b_out = (const float*)d_in[6];
  char* ws = (char*)d_ws;
  float* hid = (float*)d_out;
  float* out = hid + (size_t)TSTEPS * NBATCH * DH;
  bf16* zi = (bf16*)(ws + ZI_OFF);

  k_prep<<<dim3(3137), dim3(256), 0, stream>>>(W_in, U, V, W_out, ws);
  k_zi<<<dim3(512, 8), dim3(256), 0, stream>>>(x, ws, zi);
  k_scan<<<dim3(NBG * NGH), dim3(256), 0, stream>>>(ws, b_h);
  k_hidden<<<dim3(512, 8), dim3(256), 0, stream>>>(ws, b_h, hid);
  k_out<<<dim3(512), dim3(512), 0, stream>>>(ws, hid, b_out, out);
}